// Round 6
// baseline (808.194 us; speedup 1.0000x reference)
//
#include <hip/hip_runtime.h>
#include <hip/hip_bf16.h>
#include <math.h>

#define P 65536

typedef float f32x4 __attribute__((ext_vector_type(4)));
typedef float f32x16 __attribute__((ext_vector_type(16)));
typedef short bf16x8 __attribute__((ext_vector_type(8)));
typedef unsigned short us8 __attribute__((ext_vector_type(8)));

__device__ __forceinline__ unsigned short f2b(float f) {
    __hip_bfloat16 h = __float2bfloat16(f);   // RNE, native cvt
    return __builtin_bit_cast(unsigned short, h);
}
__device__ __forceinline__ float b2f(unsigned short h) {
    return __builtin_bit_cast(float, (unsigned)h << 16);
}
__device__ __forceinline__ int shift_src(int g, int p) {
    int h = p >> 8, w = p & 255;
    if (g == 0) return (w < 255) ? p + 1 : -1;
    if (g == 1) return (w > 0) ? p - 1 : -1;
    if (g == 2) return (h < 255) ? p + 256 : -1;
    if (g == 3) return (h > 0) ? p - 256 : -1;
    return p;
}

// ---------------------------------------------------------------------------
// x [180][65536] fp32 CHW -> A32 [65536][192] fp32 NHWC (pads zeroed)
// ---------------------------------------------------------------------------
__global__ __launch_bounds__(256) void to_nhwc(const float* __restrict__ x,
                                               float* __restrict__ A32) {
    const int p = blockIdx.x * 256 + threadIdx.x;
    #pragma unroll
    for (int c4 = 0; c4 < 45; c4++) {
        float4 v;
        v.x = x[(size_t)(c4 * 4 + 0) * P + p];
        v.y = x[(size_t)(c4 * 4 + 1) * P + p];
        v.z = x[(size_t)(c4 * 4 + 2) * P + p];
        v.w = x[(size_t)(c4 * 4 + 3) * P + p];
        *(float4*)&A32[(size_t)p * 192 + c4 * 4] = v;
    }
    float4 z = make_float4(0, 0, 0, 0);
    *(float4*)&A32[(size_t)p * 192 + 180] = z;
    *(float4*)&A32[(size_t)p * 192 + 184] = z;
    *(float4*)&A32[(size_t)p * 192 + 188] = z;
}

// A32 [65536][192] NHWC -> d_out [180][65536] CHW
__global__ __launch_bounds__(256) void from_nhwc(const float* __restrict__ A32,
                                                 float* __restrict__ out) {
    const int p = blockIdx.x * 256 + threadIdx.x;
    #pragma unroll
    for (int c4 = 0; c4 < 45; c4++) {
        float4 v = *(const float4*)&A32[(size_t)p * 192 + c4 * 4];
        out[(size_t)(c4 * 4 + 0) * P + p] = v.x;
        out[(size_t)(c4 * 4 + 1) * P + p] = v.y;
        out[(size_t)(c4 * 4 + 2) * P + p] = v.z;
        out[(size_t)(c4 * 4 + 3) * P + p] = v.w;
    }
}

// zero pad columns of Qb (ch 360..383) and Ob (ch 180..191)
__global__ __launch_bounds__(256) void padzero(unsigned short* __restrict__ Qb,
                                               unsigned short* __restrict__ Ob) {
    const int p = blockIdx.x * 256 + threadIdx.x;
    us8 z = {0, 0, 0, 0, 0, 0, 0, 0};
    *(us8*)&Qb[(size_t)p * 384 + 360] = z;
    *(us8*)&Qb[(size_t)p * 384 + 368] = z;
    *(us8*)&Qb[(size_t)p * 384 + 376] = z;
    ushort4 z4 = {0, 0, 0, 0};
    *(ushort4*)&Ob[(size_t)p * 192 + 180] = z4;
    *(ushort4*)&Ob[(size_t)p * 192 + 184] = z4;
    *(ushort4*)&Ob[(size_t)p * 192 + 188] = z4;
}

// ---------------------------------------------------------------------------
// weight convert: W [OC][K] fp32 -> Wb [384][KP] bf16, zero-padded both dims
// ---------------------------------------------------------------------------
__global__ __launch_bounds__(256) void wcvt(const float* __restrict__ W,
                                            unsigned short* __restrict__ Wb,
                                            int OC, int K, int KP) {
    const int idx = blockIdx.x * 256 + threadIdx.x;   // over 384*KP
    const int oc = idx / KP, k = idx - oc * KP;
    unsigned short v = 0;
    if (oc < OC && k < K) v = f2b(W[(size_t)oc * K + k]);
    Wb[idx] = v;
}

// ---------------------------------------------------------------------------
// mconvA: Cout=360 (padded 384), CIN=180 (KP=192). One block = 128 pix x ALL oc.
// 512 thr = 8 waves (2 pix-groups x 4 oc-groups of 48). X (full K=192) staged
// once in lx; W reg-prefetched then ds_written per 64-k chunk (2 oc-halves).
// Epilogue: fragments -> LDS buf (aliased over lw) -> fully-coalesced us8
// streams to Qb (full-line writes; pad ch 360..383 written as 0).
// EPI: 0 = BN -> Qb bf16(384)   1 = bias+GELU -> Qb bf16(384)
// ---------------------------------------------------------------------------
template<int SRCB16, int SHIFT, int EPI>
__global__ __launch_bounds__(512, 4) void mconvA(
    const void* __restrict__ Xsrc, const unsigned short* __restrict__ Wb,
    const float* __restrict__ Bi,
    const float* __restrict__ bg, const float* __restrict__ bb,
    const float* __restrict__ bm, const float* __restrict__ bv,
    unsigned short* __restrict__ Qb)
{
    __shared__ __align__(16) unsigned short lx[128][196];
    __shared__ __align__(16) unsigned short lw[192][76];   // also epilogue buf [64][200]

    const int tid = threadIdx.x;
    const int lane = tid & 63, wid = tid >> 6;
    const int wp = wid >> 2, wo = wid & 3;
    const int pbase = blockIdx.x * 128;

    // ---- stage X, full K=192, 4-wide granules (group size 36 % 4 == 0) ----
    #pragma unroll
    for (int i = 0; i < 12; i++) {
        int idx = tid + i * 512;
        int row = idx / 48, c4 = (idx % 48) * 4;
        int p = pbase + row;
        if constexpr (SRCB16) {
            const unsigned short* XB = (const unsigned short*)Xsrc;
            ushort4 hv = {0, 0, 0, 0};
            if constexpr (!SHIFT) {
                hv = *(const ushort4*)&XB[(size_t)p * 192 + c4];
            } else {
                if (c4 < 180) {
                    int sp = shift_src(c4 / 36, p);
                    if (sp >= 0) hv = *(const ushort4*)&XB[(size_t)sp * 192 + c4];
                }
            }
            *(ushort4*)&lx[row][c4] = hv;
        } else {
            const float* X32 = (const float*)Xsrc;
            float4 xv = make_float4(0, 0, 0, 0);
            if constexpr (!SHIFT) {
                xv = *(const float4*)&X32[(size_t)p * 192 + c4];
            } else {
                if (c4 < 180) {
                    int sp = shift_src(c4 / 36, p);
                    if (sp >= 0) xv = *(const float4*)&X32[(size_t)sp * 192 + c4];
                }
            }
            ushort4 b4 = {f2b(xv.x), f2b(xv.y), f2b(xv.z), f2b(xv.w)};
            *(ushort4*)&lx[row][c4] = b4;
        }
    }

    // W prefetch registers (3 x us8): thread covers (row = idx>>3, c8 = (idx&7)*8)
    const int wrow0 = tid >> 3, wc8 = (tid & 7) * 8;
    us8 wreg[3];
    #pragma unroll
    for (int i = 0; i < 3; i++)
        wreg[i] = *(const us8*)&Wb[(size_t)(wrow0 + i * 64) * 192 + wc8];

    unsigned short(*buf)[200] = (unsigned short(*)[200])&lw[0][0];   // [64][200]

    #pragma unroll
    for (int h = 0; h < 2; ++h) {
        f32x4 acc[4][3];
        #pragma unroll
        for (int a = 0; a < 4; a++)
            #pragma unroll
            for (int b = 0; b < 3; b++) acc[a][b] = (f32x4){0.f, 0.f, 0.f, 0.f};

        for (int ch = 0; ch < 3; ++ch) {
            __syncthreads();            // lw free (prev compute / epilogue done)
            #pragma unroll
            for (int i = 0; i < 3; i++)
                *(us8*)&lw[wrow0 + i * 64][wc8] = wreg[i];
            // prefetch next chunk's W (h,ch+1) or (h+1,0)
            if (!(h == 1 && ch == 2)) {
                int nh = (ch == 2) ? h + 1 : h;
                int nc = (ch == 2) ? 0 : ch + 1;
                #pragma unroll
                for (int i = 0; i < 3; i++)
                    wreg[i] = *(const us8*)&Wb[(size_t)(nh * 192 + wrow0 + i * 64) * 192 + nc * 64 + wc8];
            }
            __syncthreads();            // lw ready
            #pragma unroll
            for (int ks = 0; ks < 2; ++ks) {
                const int ko = ks * 32 + (lane >> 4) * 8;
                bf16x8 av[4], bvv[3];
                #pragma unroll
                for (int mf = 0; mf < 4; mf++)
                    av[mf] = *(const bf16x8*)&lx[wp * 64 + mf * 16 + (lane & 15)][ch * 64 + ko];
                #pragma unroll
                for (int nf = 0; nf < 3; nf++)
                    bvv[nf] = *(const bf16x8*)&lw[wo * 48 + nf * 16 + (lane & 15)][ko];
                #pragma unroll
                for (int mf = 0; mf < 4; mf++)
                    #pragma unroll
                    for (int nf = 0; nf < 3; nf++)
                        acc[mf][nf] = __builtin_amdgcn_mfma_f32_16x16x32_bf16(
                            av[mf], bvv[nf], acc[mf][nf], 0, 0, 0);
            }
        }

        // ---- epilogue for oc-half h: frag -> buf -> streamed us8 stores ----
        #pragma unroll
        for (int q = 0; q < 2; ++q) {
            __syncthreads();            // lw ds_reads done / buf free
            if (wp == q) {
                #pragma unroll
                for (int nf = 0; nf < 3; ++nf) {
                    const int col = wo * 48 + nf * 16 + (lane & 15);
                    const int oc = h * 192 + col;
                    float sc = 1.f, sh = 0.f;
                    if (oc < 360) {
                        if constexpr (EPI == 0) {
                            float inv = bg[oc] * rsqrtf(bv[oc] + 1e-5f);
                            sc = inv;
                            sh = bb[oc] + (Bi[oc] - bm[oc]) * inv;
                        } else {
                            sh = Bi[oc];
                        }
                    }
                    #pragma unroll
                    for (int mf = 0; mf < 4; ++mf) {
                        #pragma unroll
                        for (int r = 0; r < 4; ++r) {
                            const int pl = mf * 16 + (lane >> 4) * 4 + r;
                            float y = acc[mf][nf][r] * sc + sh;
                            if constexpr (EPI == 1)
                                y = 0.5f * y * (1.f + erff(y * 0.70710678118654752f));
                            buf[pl][col] = (oc < 360) ? f2b(y) : (unsigned short)0;
                        }
                    }
                }
            }
            __syncthreads();            // buf ready
            // stream out 64 rows x 192 us (= 384 B/row, rows contiguous at 768 B)
            #pragma unroll
            for (int j = 0; j < 3; ++j) {
                int idx = tid + j * 512;          // 0..1535
                int row = idx / 24, k8 = (idx % 24) * 8;
                *(us8*)&Qb[(size_t)(pbase + q * 64 + row) * 384 + h * 192 + k8] =
                    *(const us8*)&buf[row][k8];
            }
        }
    }
}

// ---------------------------------------------------------------------------
// mconvB: Cout=180 (padded 192). One block = 128 pix x all 192 oc.
// 512 thr = 8 waves (2 pix x 4 oc-groups of 48). Per-chunk lx[128][76]+lw[192][76].
// Input bf16 stride KP. EPI: 2 = bias + fp32 residual(A32) -> A32 (in-place ok)
//                          3 = bias + bf16 residual(Ob) -> A32
// ---------------------------------------------------------------------------
template<int CIN, int SHIFT, int EPI>
__global__ __launch_bounds__(512, 4) void mconvB(
    const unsigned short* __restrict__ Xb, const unsigned short* __restrict__ Wb,
    const float* __restrict__ Bi,
    const void* __restrict__ Res, float* __restrict__ A32o)
{
    constexpr int KP = (CIN == 180) ? 192 : 384;
    constexpr int NCH = KP / 64;
    constexpr int GS = CIN / 5;   // 36 or 72

    __shared__ __align__(16) unsigned short lx[128][76];
    __shared__ __align__(16) unsigned short lw[192][76];

    const int tid = threadIdx.x;
    const int lane = tid & 63, wid = tid >> 6;
    const int wp = wid >> 2, wo = wid & 3;
    const int pbase = blockIdx.x * 128;

    f32x4 acc[4][3];
    #pragma unroll
    for (int a = 0; a < 4; a++)
        #pragma unroll
        for (int b = 0; b < 3; b++) acc[a][b] = (f32x4){0.f, 0.f, 0.f, 0.f};

    for (int ch = 0; ch < NCH; ++ch) {
        const int kc0 = ch * 64;
        if (ch) __syncthreads();
        #pragma unroll
        for (int i = 0; i < 3; i++) {
            int idx = tid + i * 512;
            int row = idx >> 3, c8 = (idx & 7) * 8;
            *(us8*)&lw[row][c8] = *(const us8*)&Wb[(size_t)row * KP + kc0 + c8];
        }
        #pragma unroll
        for (int i = 0; i < 2; i++) {
            int idx = tid + i * 512;
            int row = idx >> 3, c8 = (idx & 7) * 8;
            int cc = kc0 + c8;
            int p = pbase + row;
            us8 hv = {0, 0, 0, 0, 0, 0, 0, 0};
            if constexpr (SHIFT) {
                if (cc < CIN) {
                    int sp = shift_src(cc / GS, p);
                    if (sp >= 0) hv = *(const us8*)&Xb[(size_t)sp * KP + cc];
                }
            } else {
                hv = *(const us8*)&Xb[(size_t)p * KP + cc];
            }
            *(us8*)&lx[row][c8] = hv;
        }
        __syncthreads();
        #pragma unroll
        for (int ks = 0; ks < 2; ++ks) {
            const int ko = ks * 32 + (lane >> 4) * 8;
            bf16x8 av[4], bvv[3];
            #pragma unroll
            for (int mf = 0; mf < 4; mf++)
                av[mf] = *(const bf16x8*)&lx[wp * 64 + mf * 16 + (lane & 15)][ko];
            #pragma unroll
            for (int nf = 0; nf < 3; nf++)
                bvv[nf] = *(const bf16x8*)&lw[wo * 48 + nf * 16 + (lane & 15)][ko];
            #pragma unroll
            for (int mf = 0; mf < 4; mf++)
                #pragma unroll
                for (int nf = 0; nf < 3; nf++)
                    acc[mf][nf] = __builtin_amdgcn_mfma_f32_16x16x32_bf16(
                        av[mf], bvv[nf], acc[mf][nf], 0, 0, 0);
        }
    }

    #pragma unroll
    for (int nf = 0; nf < 3; ++nf) {
        const int oc = wo * 48 + nf * 16 + (lane & 15);
        if (oc >= 180) continue;
        const float sh = Bi[oc];
        #pragma unroll
        for (int mf = 0; mf < 4; ++mf) {
            #pragma unroll
            for (int r = 0; r < 4; ++r) {
                const int pix = pbase + wp * 64 + mf * 16 + (lane >> 4) * 4 + r;
                float y = acc[mf][nf][r] + sh;
                if constexpr (EPI == 2) {
                    y += ((const float*)Res)[(size_t)pix * 192 + oc];
                } else {
                    y += b2f(((const unsigned short*)Res)[(size_t)pix * 192 + oc]);
                }
                A32o[(size_t)pix * 192 + oc] = y;
            }
        }
    }
}

// ---------------------------------------------------------------------------
// MFMA window attention via symmetric-S trick (unchanged, verified).
// ---------------------------------------------------------------------------
template<int WSZ>
__global__ __launch_bounds__(256) void mattn(const unsigned short* __restrict__ Qb,
                                             unsigned short* __restrict__ Ob, int sh)
{
    constexpr int TOK = WSZ * WSZ;
    constexpr int WPB = (WSZ == 8) ? 4 : 1;
    constexpr int NMI = TOK / 32;

    __shared__ __align__(16) unsigned short q_s[WPB][TOK][24];
    __shared__ __align__(16) unsigned short v_s[WPB][TOK][16];

    const int tid = threadIdx.x;
    const int lane = tid & 63, wid = tid >> 6;
    const int la = lane & 31, h = lane >> 5;
    const int head = blockIdx.y;
    const int qoff = ((WSZ == 8) ? 0 : 180) + head * 15;
    const int voff = qoff + 90;
    const int obase = ((WSZ == 8) ? 0 : 90) + head * 15;

    const int win = (WSZ == 8) ? (blockIdx.x * 4 + wid) : blockIdx.x;
    const int wy = win >> ((WSZ == 8) ? 5 : 4);
    const int wx = win & ((WSZ == 8) ? 31 : 15);

    {
        const int sw = (WSZ == 8) ? wid : 0;
        const int t = (WSZ == 8) ? (tid & 63) : tid;
        const int ty = t / WSZ, tx = t % WSZ;
        const int gh = (wy * WSZ + ty - sh) & 255;
        const int gw = (wx * WSZ + tx - sh) & 255;
        const unsigned short* src = Qb + (size_t)((gh << 8) | gw) * 384;
        #pragma unroll
        for (int c = 0; c < 15; c++) {
            q_s[sw][t][c] = src[qoff + c];
            v_s[sw][t][c] = src[voff + c];
        }
        q_s[sw][t][15] = 0;
        v_s[sw][t][15] = 0;
    }
    __syncthreads();

    const int mywin = (WSZ == 8) ? wid : 0;
    const unsigned short (*qs)[24] = q_s[mywin];
    const unsigned short (*vs)[16] = v_s[mywin];
    const int ni0 = (WSZ == 8) ? 0 : (wid * 2);
    const int ni1 = ni0 + 1;

    bf16x8 bfr0 = *(const bf16x8*)&qs[ni0 * 32 + la][h * 8];
    bf16x8 bfr1 = *(const bf16x8*)&qs[ni1 * 32 + la][h * 8];

    f32x16 O0, O1;
    #pragma unroll
    for (int r = 0; r < 16; r++) { O0[r] = 0.f; O1[r] = 0.f; }
    float m0 = -3.0e38f, m1 = -3.0e38f, l0 = 0.f, l1 = 0.f;

    unsigned short hw0[16], hw1[16];

    auto proc = [&](f32x16& S, float& m, float& l, f32x16& O, unsigned short* hw) {
        float vm = S[0];
        #pragma unroll
        for (int r = 1; r < 16; r++) vm = fmaxf(vm, S[r]);
        vm = fmaxf(vm, __shfl_xor(vm, 32));
        float nm = fmaxf(m, vm);
        float rs = __expf(m - nm);
        m = nm;
        l *= rs;
        #pragma unroll
        for (int r = 0; r < 16; r++) O[r] *= rs;
        float lacc = 0.f;
        #pragma unroll
        for (int r = 0; r < 16; r++) {
            unsigned short u = f2b(__expf(S[r] - nm));
            hw[r] = u;
            lacc += b2f(u);
        }
        l += lacc;
    };

    auto pack = [&](const unsigned short* hw, int sub) -> bf16x8 {
        unsigned A01 = (unsigned)hw[8 * sub + 0] | ((unsigned)hw[8 * sub + 1] << 16);
        unsigned A23 = (unsigned)hw[8 * sub + 2] | ((unsigned)hw[8 * sub + 3] << 16);
        unsigned B01 = (unsigned)hw[8 * sub + 4] | ((unsigned)hw[8 * sub + 5] << 16);
        unsigned B23 = (unsigned)hw[8 * sub + 6] | ((unsigned)hw[8 * sub + 7] << 16);
        unsigned x1 = (unsigned)__shfl_xor((int)(h ? A01 : B01), 32);
        unsigned x2 = (unsigned)__shfl_xor((int)(h ? A23 : B23), 32);
        union { unsigned u[4]; bf16x8 v; } pf;
        pf.u[0] = h ? x1 : A01;
        pf.u[1] = h ? x2 : A23;
        pf.u[2] = h ? B01 : x1;
        pf.u[3] = h ? B23 : x2;
        return pf.v;
    };

    for (int mi = 0; mi < NMI; ++mi) {
        bf16x8 af = *(const bf16x8*)&qs[mi * 32 + la][h * 8];
        f32x16 z;
        #pragma unroll
        for (int r = 0; r < 16; r++) z[r] = 0.f;
        f32x16 s0 = __builtin_amdgcn_mfma_f32_32x32x16_bf16(af, bfr0, z, 0, 0, 0);
        f32x16 s1 = __builtin_amdgcn_mfma_f32_32x32x16_bf16(af, bfr1, z, 0, 0, 0);

        proc(s0, m0, l0, O0, hw0);
        proc(s1, m1, l1, O1, hw1);

        #pragma unroll
        for (int sub = 0; sub < 2; ++sub) {
            union { unsigned short us[8]; bf16x8 v; } av;
            #pragma unroll
            for (int j = 0; j < 8; j++)
                av.us[j] = vs[mi * 32 + sub * 16 + h * 8 + j][la & 15];
            bf16x8 pf0 = pack(hw0, sub);
            bf16x8 pf1 = pack(hw1, sub);
            O0 = __builtin_amdgcn_mfma_f32_32x32x16_bf16(av.v, pf0, O0, 0, 0, 0);
            O1 = __builtin_amdgcn_mfma_f32_32x32x16_bf16(av.v, pf1, O1, 0, 0, 0);
        }
    }

    #pragma unroll
    for (int t = 0; t < 2; ++t) {
        const f32x16& O = t ? O1 : O0;
        float l = t ? l1 : l0;
        const int ni = t ? ni1 : ni0;
        float lt = l + __shfl_xor(l, 32);
        float inv = 1.f / lt;
        const int R = ni * 32 + la;
        const int ty = R / WSZ, tx = R % WSZ;
        const int gh = (wy * WSZ + ty - sh) & 255;
        const int gw = (wx * WSZ + tx - sh) & 255;
        unsigned short* dst = Ob + (size_t)((gh << 8) | gw) * 192 + obase;
        #pragma unroll
        for (int reg = 0; reg < 16; ++reg) {
            const int ch = (reg & 3) + 8 * (reg >> 2) + 4 * h;
            if (ch < 15) dst[ch] = f2b(O[reg] * inv);
        }
    }
}

// ---------------------------------------------------------------------------
// pixel mixer: Ob = bf16( x + BN(pm(x) - x) ), x = A32 (NHWC). Circular rolls.
// ---------------------------------------------------------------------------
__global__ __launch_bounds__(256) void pixmixk(const float* __restrict__ A32,
    const float* __restrict__ g, const float* __restrict__ b,
    const float* __restrict__ m, const float* __restrict__ v,
    unsigned short* __restrict__ Ob)
{
    const int idx = blockIdx.x * 256 + threadIdx.x; // 65536*45
    const int p = idx / 45;
    const int c0 = (idx - p * 45) * 4;
    const int h = p >> 8, w = p & 255;
    float4 x = *(const float4*)&A32[(size_t)p * 192 + c0];
    ushort4 o;
    #pragma unroll
    for (int j = 0; j < 4; j++) {
        int c = c0 + j;
        int gr = c - (c / 5) * 5;
        int sp;
        if (gr == 0)      sp = (h << 8) | ((w + 1) & 255);
        else if (gr == 1) sp = (h << 8) | ((w - 1) & 255);
        else if (gr == 2) sp = (((h + 1) & 255) << 8) | w;
        else if (gr == 3) sp = (((h - 1) & 255) << 8) | w;
        else              sp = p;
        float pm = A32[(size_t)sp * 192 + c];
        float xv = (j == 0) ? x.x : (j == 1) ? x.y : (j == 2) ? x.z : x.w;
        float inv = g[c] * rsqrtf(v[c] + 1e-5f);
        float y = xv + (pm - xv - m[c]) * inv + b[c];
        ((unsigned short*)&o)[j] = f2b(y);
    }
    *(ushort4*)&Ob[(size_t)p * 192 + c0] = o;
}

extern "C" void kernel_launch(void* const* d_in, const int* in_sizes, int n_in,
                              void* d_out, int out_size, void* d_ws, size_t ws_size,
                              hipStream_t stream)
{
    const float* x        = (const float*)d_in[0];
    const float* a0_qkv_w = (const float*)d_in[1];
    const float* a0_qkv_b = (const float*)d_in[2];
    const float* a0_bn_g  = (const float*)d_in[3];
    const float* a0_bn_b  = (const float*)d_in[4];
    const float* a0_bn_m  = (const float*)d_in[5];
    const float* a0_bn_v  = (const float*)d_in[6];
    const float* a0_proj_w= (const float*)d_in[7];
    const float* a0_proj_b= (const float*)d_in[8];
    const float* a1_qkv_w = (const float*)d_in[9];
    const float* a1_qkv_b = (const float*)d_in[10];
    const float* a1_bn_g  = (const float*)d_in[11];
    const float* a1_bn_b  = (const float*)d_in[12];
    const float* a1_bn_m  = (const float*)d_in[13];
    const float* a1_bn_v  = (const float*)d_in[14];
    const float* a1_proj_w= (const float*)d_in[15];
    const float* a1_proj_b= (const float*)d_in[16];
    const float* t2_bn_g  = (const float*)d_in[17];
    const float* t2_bn_b  = (const float*)d_in[18];
    const float* t2_bn_m  = (const float*)d_in[19];
    const float* t2_bn_v  = (const float*)d_in[20];
    const float* m0_fc1_w = (const float*)d_in[21];
    const float* m0_fc1_b = (const float*)d_in[22];
    const float* m0_fc2_w = (const float*)d_in[23];
    const float* m0_fc2_b = (const float*)d_in[24];
    const float* m1_fc1_w = (const float*)d_in[25];
    const float* m1_fc1_b = (const float*)d_in[26];
    const float* m1_fc2_w = (const float*)d_in[27];
    const float* m1_fc2_b = (const float*)d_in[28];
    const float* m2_fc1_w = (const float*)d_in[29];
    const float* m2_fc1_b = (const float*)d_in[30];
    const float* m2_fc2_w = (const float*)d_in[31];
    const float* m2_fc2_b = (const float*)d_in[32];

    unsigned short* Qb  = (unsigned short*)d_ws;                   // [P][384] bf16
    unsigned short* Ob  = Qb + (size_t)P * 384;                    // [P][192] bf16
    float*          A32 = (float*)(Ob + (size_t)P * 192);          // [P][192] fp32
    unsigned short* Wp  = (unsigned short*)(A32 + (size_t)P * 192);
    const size_t W192 = 384 * 192, W384 = (size_t)384 * 384;
    unsigned short* wb_qkv0 = Wp;
    unsigned short* wb_prj0 = wb_qkv0 + W192;
    unsigned short* wb_qkv1 = wb_prj0 + W192;
    unsigned short* wb_prj1 = wb_qkv1 + W192;
    unsigned short* wb_fc1_0 = wb_prj1 + W192;
    unsigned short* wb_fc1_1 = wb_fc1_0 + W192;
    unsigned short* wb_fc1_2 = wb_fc1_1 + W192;
    unsigned short* wb_fc2_0 = wb_fc1_2 + W192;
    unsigned short* wb_fc2_1 = wb_fc2_0 + W384;
    unsigned short* wb_fc2_2 = wb_fc2_1 + W384;

    dim3 blk(256);
    dim3 blk512(512);
    dim3 gpix(256);
    dim3 gconv(512);
    dim3 ga8(256, 6);
    dim3 ga16(256, 6);

    // ---- one-time prep ----
    wcvt<<<288, blk, 0, stream>>>(a0_qkv_w, wb_qkv0, 360, 180, 192);
    wcvt<<<288, blk, 0, stream>>>(a0_proj_w, wb_prj0, 180, 180, 192);
    wcvt<<<288, blk, 0, stream>>>(a1_qkv_w, wb_qkv1, 360, 180, 192);
    wcvt<<<288, blk, 0, stream>>>(a1_proj_w, wb_prj1, 180, 180, 192);
    wcvt<<<288, blk, 0, stream>>>(m0_fc1_w, wb_fc1_0, 360, 180, 192);
    wcvt<<<288, blk, 0, stream>>>(m1_fc1_w, wb_fc1_1, 360, 180, 192);
    wcvt<<<288, blk, 0, stream>>>(m2_fc1_w, wb_fc1_2, 360, 180, 192);
    wcvt<<<576, blk, 0, stream>>>(m0_fc2_w, wb_fc2_0, 180, 360, 384);
    wcvt<<<576, blk, 0, stream>>>(m1_fc2_w, wb_fc2_1, 180, 360, 384);
    wcvt<<<576, blk, 0, stream>>>(m2_fc2_w, wb_fc2_2, 180, 360, 384);
    padzero<<<gpix, blk, 0, stream>>>(Qb, Ob);
    to_nhwc<<<gpix, blk, 0, stream>>>(x, A32);

    // ---- attn stage 0 ----
    mconvA<0,0,0><<<gconv, blk512, 0, stream>>>(A32, wb_qkv0, a0_qkv_b,
        a0_bn_g, a0_bn_b, a0_bn_m, a0_bn_v, Qb);
    mattn<8> <<<ga8,  blk, 0, stream>>>(Qb, Ob, 0);
    mattn<16><<<ga16, blk, 0, stream>>>(Qb, Ob, 0);
    mconvB<180,0,2><<<gconv, blk512, 0, stream>>>(Ob, wb_prj0, a0_proj_b, A32, A32);

    // ---- mlp0 ----
    mconvA<0,1,1><<<gconv, blk512, 0, stream>>>(A32, wb_fc1_0, m0_fc1_b,
        nullptr, nullptr, nullptr, nullptr, Qb);
    mconvB<360,1,2><<<gconv, blk512, 0, stream>>>(Qb, wb_fc2_0, m0_fc2_b, A32, A32);

    // ---- attn stage 1 ----
    mconvA<0,0,0><<<gconv, blk512, 0, stream>>>(A32, wb_qkv1, a1_qkv_b,
        a1_bn_g, a1_bn_b, a1_bn_m, a1_bn_v, Qb);
    mattn<8> <<<ga8,  blk, 0, stream>>>(Qb, Ob, 4);
    mattn<16><<<ga16, blk, 0, stream>>>(Qb, Ob, 8);
    mconvB<180,0,2><<<gconv, blk512, 0, stream>>>(Ob, wb_prj1, a1_proj_b, A32, A32);

    // ---- mlp1 ----
    mconvA<0,1,1><<<gconv, blk512, 0, stream>>>(A32, wb_fc1_1, m1_fc1_b,
        nullptr, nullptr, nullptr, nullptr, Qb);
    mconvB<360,1,2><<<gconv, blk512, 0, stream>>>(Qb, wb_fc2_1, m1_fc2_b, A32, A32);

    // ---- pixel mixer: Ob = bf16(x5) ----
    pixmixk<<<dim3(65536 * 45 / 256), blk, 0, stream>>>(A32, t2_bn_g, t2_bn_b,
        t2_bn_m, t2_bn_v, Ob);

    // ---- mlp2 (input Ob bf16 shifted; residual Ob bf16) ----
    mconvA<1,1,1><<<gconv, blk512, 0, stream>>>(Ob, wb_fc1_2, m2_fc1_b,
        nullptr, nullptr, nullptr, nullptr, Qb);
    mconvB<360,1,3><<<gconv, blk512, 0, stream>>>(Qb, wb_fc2_2, m2_fc2_b, Ob, A32);

    from_nhwc<<<gpix, blk, 0, stream>>>(A32, (float*)d_out);
}

// Round 7
// 653.608 us; speedup vs baseline: 1.2365x; 1.2365x over previous
//
#include <hip/hip_runtime.h>
#include <hip/hip_bf16.h>
#include <math.h>

#define P 65536

typedef float f32x4 __attribute__((ext_vector_type(4)));
typedef float f32x16 __attribute__((ext_vector_type(16)));
typedef short bf16x8 __attribute__((ext_vector_type(8)));
typedef unsigned short us8 __attribute__((ext_vector_type(8)));

__device__ __forceinline__ unsigned short f2b(float f) {
    __hip_bfloat16 h = __float2bfloat16(f);   // RNE, native cvt
    return __builtin_bit_cast(unsigned short, h);
}
__device__ __forceinline__ float b2f(unsigned short h) {
    return __builtin_bit_cast(float, (unsigned)h << 16);
}
__device__ __forceinline__ int shift_src(int g, int p) {
    int h = p >> 8, w = p & 255;
    if (g == 0) return (w < 255) ? p + 1 : -1;
    if (g == 1) return (w > 0) ? p - 1 : -1;
    if (g == 2) return (h < 255) ? p + 256 : -1;
    if (g == 3) return (h > 0) ? p - 256 : -1;
    return p;
}

// ---------------------------------------------------------------------------
// x [180][65536] fp32 CHW -> A32 [65536][192] fp32 NHWC (pads zeroed)
// ---------------------------------------------------------------------------
__global__ __launch_bounds__(256) void to_nhwc(const float* __restrict__ x,
                                               float* __restrict__ A32) {
    const int p = blockIdx.x * 256 + threadIdx.x;
    #pragma unroll
    for (int c4 = 0; c4 < 45; c4++) {
        float4 v;
        v.x = x[(size_t)(c4 * 4 + 0) * P + p];
        v.y = x[(size_t)(c4 * 4 + 1) * P + p];
        v.z = x[(size_t)(c4 * 4 + 2) * P + p];
        v.w = x[(size_t)(c4 * 4 + 3) * P + p];
        *(float4*)&A32[(size_t)p * 192 + c4 * 4] = v;
    }
    float4 z = make_float4(0, 0, 0, 0);
    *(float4*)&A32[(size_t)p * 192 + 180] = z;
    *(float4*)&A32[(size_t)p * 192 + 184] = z;
    *(float4*)&A32[(size_t)p * 192 + 188] = z;
}

// A32 [65536][192] NHWC -> d_out [180][65536] CHW
__global__ __launch_bounds__(256) void from_nhwc(const float* __restrict__ A32,
                                                 float* __restrict__ out) {
    const int p = blockIdx.x * 256 + threadIdx.x;
    #pragma unroll
    for (int c4 = 0; c4 < 45; c4++) {
        float4 v = *(const float4*)&A32[(size_t)p * 192 + c4 * 4];
        out[(size_t)(c4 * 4 + 0) * P + p] = v.x;
        out[(size_t)(c4 * 4 + 1) * P + p] = v.y;
        out[(size_t)(c4 * 4 + 2) * P + p] = v.z;
        out[(size_t)(c4 * 4 + 3) * P + p] = v.w;
    }
}

// zero pad columns of Ob (ch 180..191)
__global__ __launch_bounds__(256) void padzero(unsigned short* __restrict__ Ob) {
    const int p = blockIdx.x * 256 + threadIdx.x;
    ushort4 z4 = {0, 0, 0, 0};
    *(ushort4*)&Ob[(size_t)p * 192 + 180] = z4;
    *(ushort4*)&Ob[(size_t)p * 192 + 184] = z4;
    *(ushort4*)&Ob[(size_t)p * 192 + 188] = z4;
}

// ---------------------------------------------------------------------------
// weight convert: W [OC][K] fp32 -> Wb [384][KP] bf16, zero-padded both dims
// ---------------------------------------------------------------------------
__global__ __launch_bounds__(256) void wcvt(const float* __restrict__ W,
                                            unsigned short* __restrict__ Wb,
                                            int OC, int K, int KP) {
    const int idx = blockIdx.x * 256 + threadIdx.x;   // over 384*KP
    const int oc = idx / KP, k = idx - oc * KP;
    unsigned short v = 0;
    if (oc < OC && k < K) v = f2b(W[(size_t)oc * K + k]);
    Wb[idx] = v;
}

// ---------------------------------------------------------------------------
// mconvA2: Cout=360 (padded 384), CIN=180 (KP=192), output bf16 Qb[384].
// mconvB-shaped: grid (pix-tiles, 2 oc-halves); block = 128 pix x 192 oc,
// 8 waves (4 oc-groups x 2 pix-groups), per-64k-chunk staging, 2 barriers/chunk.
// OPERAND-SWAPPED MFMA (A=W, B=X) => C[oc][pix]: lane holds 4 consecutive
// channels of one pixel -> single ushort4 (8B) store per fragment.
// EPI: 0 = BN -> Qb   1 = bias+GELU -> Qb.  oc>=360 lanes write zeros (pads).
// ---------------------------------------------------------------------------
template<int SRCB16, int SHIFT, int EPI>
__global__ __launch_bounds__(512, 4) void mconvA2(
    const void* __restrict__ Xsrc, const unsigned short* __restrict__ Wb,
    const float* __restrict__ Bi,
    const float* __restrict__ bg, const float* __restrict__ bb,
    const float* __restrict__ bm, const float* __restrict__ bv,
    unsigned short* __restrict__ Qb)
{
    __shared__ __align__(16) unsigned short lx[128][76];
    __shared__ __align__(16) unsigned short lw[192][76];

    const int tid = threadIdx.x;
    const int lane = tid & 63, wid = tid >> 6;
    const int wp = wid >> 2, wo = wid & 3;
    const int pbase = blockIdx.x * 128;
    const int obase = blockIdx.y * 192;

    f32x4 acc[3][4];   // [oc-frag][pix-frag]
    #pragma unroll
    for (int a = 0; a < 3; a++)
        #pragma unroll
        for (int b = 0; b < 4; b++) acc[a][b] = (f32x4){0.f, 0.f, 0.f, 0.f};

    for (int ch = 0; ch < 3; ++ch) {
        const int kc0 = ch * 64;
        if (ch) __syncthreads();
        // ---- stage W chunk [192 oc][64 k] ----
        #pragma unroll
        for (int i = 0; i < 3; i++) {
            int idx = tid + i * 512;
            int row = idx >> 3, c8 = (idx & 7) * 8;
            *(us8*)&lw[row][c8] =
                *(const us8*)&Wb[(size_t)(obase + row) * 192 + kc0 + c8];
        }
        // ---- stage X chunk [128 pix][64 k], 4-wide granules (36 % 4 == 0) ----
        #pragma unroll
        for (int i = 0; i < 4; i++) {
            int idx = tid + i * 512;
            int row = idx >> 4, c4 = kc0 + (idx & 15) * 4;
            int p = pbase + row;
            if constexpr (SRCB16) {
                const unsigned short* XB = (const unsigned short*)Xsrc;
                ushort4 hv = {0, 0, 0, 0};
                if constexpr (!SHIFT) {
                    hv = *(const ushort4*)&XB[(size_t)p * 192 + c4];
                } else {
                    if (c4 < 180) {
                        int sp = shift_src(c4 / 36, p);
                        if (sp >= 0) hv = *(const ushort4*)&XB[(size_t)sp * 192 + c4];
                    }
                }
                *(ushort4*)&lx[row][c4 - kc0] = hv;
            } else {
                const float* X32 = (const float*)Xsrc;
                float4 xv = make_float4(0, 0, 0, 0);
                if constexpr (!SHIFT) {
                    xv = *(const float4*)&X32[(size_t)p * 192 + c4];
                } else {
                    if (c4 < 180) {
                        int sp = shift_src(c4 / 36, p);
                        if (sp >= 0) xv = *(const float4*)&X32[(size_t)sp * 192 + c4];
                    }
                }
                ushort4 b4 = {f2b(xv.x), f2b(xv.y), f2b(xv.z), f2b(xv.w)};
                *(ushort4*)&lx[row][c4 - kc0] = b4;
            }
        }
        __syncthreads();
        // ---- compute: 2 k-steps of 32 ----
        #pragma unroll
        for (int ks = 0; ks < 2; ++ks) {
            const int ko = ks * 32 + (lane >> 4) * 8;
            bf16x8 av[3], bvv[4];
            #pragma unroll
            for (int m = 0; m < 3; m++)
                av[m] = *(const bf16x8*)&lw[wo * 48 + m * 16 + (lane & 15)][ko];
            #pragma unroll
            for (int n = 0; n < 4; n++)
                bvv[n] = *(const bf16x8*)&lx[wp * 64 + n * 16 + (lane & 15)][ko];
            #pragma unroll
            for (int m = 0; m < 3; m++)
                #pragma unroll
                for (int n = 0; n < 4; n++)
                    acc[m][n] = __builtin_amdgcn_mfma_f32_16x16x32_bf16(
                        av[m], bvv[n], acc[m][n], 0, 0, 0);
        }
    }

    // ---- epilogue: lane = pixel, regs = 4 consecutive channels -> 8B stores ----
    #pragma unroll
    for (int m = 0; m < 3; ++m) {
        const int oc0 = obase + wo * 48 + m * 16 + ((lane >> 4) * 4);
        const bool valid = (oc0 < 360);
        float sc[4] = {1.f, 1.f, 1.f, 1.f}, sh[4] = {0.f, 0.f, 0.f, 0.f};
        if (valid) {
            float4 bi = *(const float4*)&Bi[oc0];
            if constexpr (EPI == 0) {
                float4 g4 = *(const float4*)&bg[oc0];
                float4 b4 = *(const float4*)&bb[oc0];
                float4 m4 = *(const float4*)&bm[oc0];
                float4 v4 = *(const float4*)&bv[oc0];
                #pragma unroll
                for (int r = 0; r < 4; r++) {
                    float g = (r == 0) ? g4.x : (r == 1) ? g4.y : (r == 2) ? g4.z : g4.w;
                    float b = (r == 0) ? b4.x : (r == 1) ? b4.y : (r == 2) ? b4.z : b4.w;
                    float mm = (r == 0) ? m4.x : (r == 1) ? m4.y : (r == 2) ? m4.z : m4.w;
                    float vv = (r == 0) ? v4.x : (r == 1) ? v4.y : (r == 2) ? v4.z : v4.w;
                    float bb_ = (r == 0) ? bi.x : (r == 1) ? bi.y : (r == 2) ? bi.z : bi.w;
                    float inv = g * rsqrtf(vv + 1e-5f);
                    sc[r] = inv;
                    sh[r] = b + (bb_ - mm) * inv;
                }
            } else {
                sh[0] = bi.x; sh[1] = bi.y; sh[2] = bi.z; sh[3] = bi.w;
            }
        }
        #pragma unroll
        for (int n = 0; n < 4; ++n) {
            const int pix = pbase + wp * 64 + n * 16 + (lane & 15);
            ushort4 o = {0, 0, 0, 0};
            if (valid) {
                #pragma unroll
                for (int r = 0; r < 4; ++r) {
                    float y = acc[m][n][r] * sc[r] + sh[r];
                    if constexpr (EPI == 1)
                        y = 0.5f * y * (1.f + erff(y * 0.70710678118654752f));
                    ((unsigned short*)&o)[r] = f2b(y);
                }
            }
            *(ushort4*)&Qb[(size_t)pix * 384 + oc0] = o;
        }
    }
}

// ---------------------------------------------------------------------------
// mconvB: Cout=180 (padded 192). One block = 128 pix x all 192 oc.
// 512 thr = 8 waves (2 pix x 4 oc-groups of 48). Per-chunk lx[128][76]+lw[192][76].
// Input bf16 stride KP. EPI: 2 = bias + fp32 residual(A32) -> A32 (in-place ok)
//                          3 = bias + bf16 residual(Ob) -> A32
// ---------------------------------------------------------------------------
template<int CIN, int SHIFT, int EPI>
__global__ __launch_bounds__(512, 4) void mconvB(
    const unsigned short* __restrict__ Xb, const unsigned short* __restrict__ Wb,
    const float* __restrict__ Bi,
    const void* __restrict__ Res, float* __restrict__ A32o)
{
    constexpr int KP = (CIN == 180) ? 192 : 384;
    constexpr int NCH = KP / 64;
    constexpr int GS = CIN / 5;   // 36 or 72

    __shared__ __align__(16) unsigned short lx[128][76];
    __shared__ __align__(16) unsigned short lw[192][76];

    const int tid = threadIdx.x;
    const int lane = tid & 63, wid = tid >> 6;
    const int wp = wid >> 2, wo = wid & 3;
    const int pbase = blockIdx.x * 128;

    f32x4 acc[4][3];
    #pragma unroll
    for (int a = 0; a < 4; a++)
        #pragma unroll
        for (int b = 0; b < 3; b++) acc[a][b] = (f32x4){0.f, 0.f, 0.f, 0.f};

    for (int ch = 0; ch < NCH; ++ch) {
        const int kc0 = ch * 64;
        if (ch) __syncthreads();
        #pragma unroll
        for (int i = 0; i < 3; i++) {
            int idx = tid + i * 512;
            int row = idx >> 3, c8 = (idx & 7) * 8;
            *(us8*)&lw[row][c8] = *(const us8*)&Wb[(size_t)row * KP + kc0 + c8];
        }
        #pragma unroll
        for (int i = 0; i < 2; i++) {
            int idx = tid + i * 512;
            int row = idx >> 3, c8 = (idx & 7) * 8;
            int cc = kc0 + c8;
            int p = pbase + row;
            us8 hv = {0, 0, 0, 0, 0, 0, 0, 0};
            if constexpr (SHIFT) {
                if (cc < CIN) {
                    int sp = shift_src(cc / GS, p);
                    if (sp >= 0) hv = *(const us8*)&Xb[(size_t)sp * KP + cc];
                }
            } else {
                hv = *(const us8*)&Xb[(size_t)p * KP + cc];
            }
            *(us8*)&lx[row][c8] = hv;
        }
        __syncthreads();
        #pragma unroll
        for (int ks = 0; ks < 2; ++ks) {
            const int ko = ks * 32 + (lane >> 4) * 8;
            bf16x8 av[4], bvv[3];
            #pragma unroll
            for (int mf = 0; mf < 4; mf++)
                av[mf] = *(const bf16x8*)&lx[wp * 64 + mf * 16 + (lane & 15)][ko];
            #pragma unroll
            for (int nf = 0; nf < 3; nf++)
                bvv[nf] = *(const bf16x8*)&lw[wo * 48 + nf * 16 + (lane & 15)][ko];
            #pragma unroll
            for (int mf = 0; mf < 4; mf++)
                #pragma unroll
                for (int nf = 0; nf < 3; nf++)
                    acc[mf][nf] = __builtin_amdgcn_mfma_f32_16x16x32_bf16(
                        av[mf], bvv[nf], acc[mf][nf], 0, 0, 0);
        }
    }

    #pragma unroll
    for (int nf = 0; nf < 3; ++nf) {
        const int oc = wo * 48 + nf * 16 + (lane & 15);
        if (oc >= 180) continue;
        const float sh = Bi[oc];
        #pragma unroll
        for (int mf = 0; mf < 4; ++mf) {
            #pragma unroll
            for (int r = 0; r < 4; ++r) {
                const int pix = pbase + wp * 64 + mf * 16 + (lane >> 4) * 4 + r;
                float y = acc[mf][nf][r] + sh;
                if constexpr (EPI == 2) {
                    y += ((const float*)Res)[(size_t)pix * 192 + oc];
                } else {
                    y += b2f(((const unsigned short*)Res)[(size_t)pix * 192 + oc]);
                }
                A32o[(size_t)pix * 192 + oc] = y;
            }
        }
    }
}

// ---------------------------------------------------------------------------
// MFMA window attention via symmetric-S trick (unchanged, verified).
// ---------------------------------------------------------------------------
template<int WSZ>
__global__ __launch_bounds__(256) void mattn(const unsigned short* __restrict__ Qb,
                                             unsigned short* __restrict__ Ob, int sh)
{
    constexpr int TOK = WSZ * WSZ;
    constexpr int WPB = (WSZ == 8) ? 4 : 1;
    constexpr int NMI = TOK / 32;

    __shared__ __align__(16) unsigned short q_s[WPB][TOK][24];
    __shared__ __align__(16) unsigned short v_s[WPB][TOK][16];

    const int tid = threadIdx.x;
    const int lane = tid & 63, wid = tid >> 6;
    const int la = lane & 31, h = lane >> 5;
    const int head = blockIdx.y;
    const int qoff = ((WSZ == 8) ? 0 : 180) + head * 15;
    const int voff = qoff + 90;
    const int obase = ((WSZ == 8) ? 0 : 90) + head * 15;

    const int win = (WSZ == 8) ? (blockIdx.x * 4 + wid) : blockIdx.x;
    const int wy = win >> ((WSZ == 8) ? 5 : 4);
    const int wx = win & ((WSZ == 8) ? 31 : 15);

    {
        const int sw = (WSZ == 8) ? wid : 0;
        const int t = (WSZ == 8) ? (tid & 63) : tid;
        const int ty = t / WSZ, tx = t % WSZ;
        const int gh = (wy * WSZ + ty - sh) & 255;
        const int gw = (wx * WSZ + tx - sh) & 255;
        const unsigned short* src = Qb + (size_t)((gh << 8) | gw) * 384;
        #pragma unroll
        for (int c = 0; c < 15; c++) {
            q_s[sw][t][c] = src[qoff + c];
            v_s[sw][t][c] = src[voff + c];
        }
        q_s[sw][t][15] = 0;
        v_s[sw][t][15] = 0;
    }
    __syncthreads();

    const int mywin = (WSZ == 8) ? wid : 0;
    const unsigned short (*qs)[24] = q_s[mywin];
    const unsigned short (*vs)[16] = v_s[mywin];
    const int ni0 = (WSZ == 8) ? 0 : (wid * 2);
    const int ni1 = ni0 + 1;

    bf16x8 bfr0 = *(const bf16x8*)&qs[ni0 * 32 + la][h * 8];
    bf16x8 bfr1 = *(const bf16x8*)&qs[ni1 * 32 + la][h * 8];

    f32x16 O0, O1;
    #pragma unroll
    for (int r = 0; r < 16; r++) { O0[r] = 0.f; O1[r] = 0.f; }
    float m0 = -3.0e38f, m1 = -3.0e38f, l0 = 0.f, l1 = 0.f;

    unsigned short hw0[16], hw1[16];

    auto proc = [&](f32x16& S, float& m, float& l, f32x16& O, unsigned short* hw) {
        float vm = S[0];
        #pragma unroll
        for (int r = 1; r < 16; r++) vm = fmaxf(vm, S[r]);
        vm = fmaxf(vm, __shfl_xor(vm, 32));
        float nm = fmaxf(m, vm);
        float rs = __expf(m - nm);
        m = nm;
        l *= rs;
        #pragma unroll
        for (int r = 0; r < 16; r++) O[r] *= rs;
        float lacc = 0.f;
        #pragma unroll
        for (int r = 0; r < 16; r++) {
            unsigned short u = f2b(__expf(S[r] - nm));
            hw[r] = u;
            lacc += b2f(u);
        }
        l += lacc;
    };

    auto pack = [&](const unsigned short* hw, int sub) -> bf16x8 {
        unsigned A01 = (unsigned)hw[8 * sub + 0] | ((unsigned)hw[8 * sub + 1] << 16);
        unsigned A23 = (unsigned)hw[8 * sub + 2] | ((unsigned)hw[8 * sub + 3] << 16);
        unsigned B01 = (unsigned)hw[8 * sub + 4] | ((unsigned)hw[8 * sub + 5] << 16);
        unsigned B23 = (unsigned)hw[8 * sub + 6] | ((unsigned)hw[8 * sub + 7] << 16);
        unsigned x1 = (unsigned)__shfl_xor((int)(h ? A01 : B01), 32);
        unsigned x2 = (unsigned)__shfl_xor((int)(h ? A23 : B23), 32);
        union { unsigned u[4]; bf16x8 v; } pf;
        pf.u[0] = h ? x1 : A01;
        pf.u[1] = h ? x2 : A23;
        pf.u[2] = h ? B01 : x1;
        pf.u[3] = h ? B23 : x2;
        return pf.v;
    };

    for (int mi = 0; mi < NMI; ++mi) {
        bf16x8 af = *(const bf16x8*)&qs[mi * 32 + la][h * 8];
        f32x16 z;
        #pragma unroll
        for (int r = 0; r < 16; r++) z[r] = 0.f;
        f32x16 s0 = __builtin_amdgcn_mfma_f32_32x32x16_bf16(af, bfr0, z, 0, 0, 0);
        f32x16 s1 = __builtin_amdgcn_mfma_f32_32x32x16_bf16(af, bfr1, z, 0, 0, 0);

        proc(s0, m0, l0, O0, hw0);
        proc(s1, m1, l1, O1, hw1);

        #pragma unroll
        for (int sub = 0; sub < 2; ++sub) {
            union { unsigned short us[8]; bf16x8 v; } av;
            #pragma unroll
            for (int j = 0; j < 8; j++)
                av.us[j] = vs[mi * 32 + sub * 16 + h * 8 + j][la & 15];
            bf16x8 pf0 = pack(hw0, sub);
            bf16x8 pf1 = pack(hw1, sub);
            O0 = __builtin_amdgcn_mfma_f32_32x32x16_bf16(av.v, pf0, O0, 0, 0, 0);
            O1 = __builtin_amdgcn_mfma_f32_32x32x16_bf16(av.v, pf1, O1, 0, 0, 0);
        }
    }

    #pragma unroll
    for (int t = 0; t < 2; ++t) {
        const f32x16& O = t ? O1 : O0;
        float l = t ? l1 : l0;
        const int ni = t ? ni1 : ni0;
        float lt = l + __shfl_xor(l, 32);
        float inv = 1.f / lt;
        const int R = ni * 32 + la;
        const int ty = R / WSZ, tx = R % WSZ;
        const int gh = (wy * WSZ + ty - sh) & 255;
        const int gw = (wx * WSZ + tx - sh) & 255;
        unsigned short* dst = Ob + (size_t)((gh << 8) | gw) * 192 + obase;
        #pragma unroll
        for (int reg = 0; reg < 16; ++reg) {
            const int ch = (reg & 3) + 8 * (reg >> 2) + 4 * h;
            if (ch < 15) dst[ch] = f2b(O[reg] * inv);
        }
    }
}

// ---------------------------------------------------------------------------
// pixel mixer: Ob = bf16( x + BN(pm(x) - x) ), x = A32 (NHWC). Circular rolls.
// ---------------------------------------------------------------------------
__global__ __launch_bounds__(256) void pixmixk(const float* __restrict__ A32,
    const float* __restrict__ g, const float* __restrict__ b,
    const float* __restrict__ m, const float* __restrict__ v,
    unsigned short* __restrict__ Ob)
{
    const int idx = blockIdx.x * 256 + threadIdx.x; // 65536*45
    const int p = idx / 45;
    const int c0 = (idx - p * 45) * 4;
    const int h = p >> 8, w = p & 255;
    float4 x = *(const float4*)&A32[(size_t)p * 192 + c0];
    ushort4 o;
    #pragma unroll
    for (int j = 0; j < 4; j++) {
        int c = c0 + j;
        int gr = c - (c / 5) * 5;
        int sp;
        if (gr == 0)      sp = (h << 8) | ((w + 1) & 255);
        else if (gr == 1) sp = (h << 8) | ((w - 1) & 255);
        else if (gr == 2) sp = (((h + 1) & 255) << 8) | w;
        else if (gr == 3) sp = (((h - 1) & 255) << 8) | w;
        else              sp = p;
        float pm = A32[(size_t)sp * 192 + c];
        float xv = (j == 0) ? x.x : (j == 1) ? x.y : (j == 2) ? x.z : x.w;
        float inv = g[c] * rsqrtf(v[c] + 1e-5f);
        float y = xv + (pm - xv - m[c]) * inv + b[c];
        ((unsigned short*)&o)[j] = f2b(y);
    }
    *(ushort4*)&Ob[(size_t)p * 192 + c0] = o;
}

extern "C" void kernel_launch(void* const* d_in, const int* in_sizes, int n_in,
                              void* d_out, int out_size, void* d_ws, size_t ws_size,
                              hipStream_t stream)
{
    const float* x        = (const float*)d_in[0];
    const float* a0_qkv_w = (const float*)d_in[1];
    const float* a0_qkv_b = (const float*)d_in[2];
    const float* a0_bn_g  = (const float*)d_in[3];
    const float* a0_bn_b  = (const float*)d_in[4];
    const float* a0_bn_m  = (const float*)d_in[5];
    const float* a0_bn_v  = (const float*)d_in[6];
    const float* a0_proj_w= (const float*)d_in[7];
    const float* a0_proj_b= (const float*)d_in[8];
    const float* a1_qkv_w = (const float*)d_in[9];
    const float* a1_qkv_b = (const float*)d_in[10];
    const float* a1_bn_g  = (const float*)d_in[11];
    const float* a1_bn_b  = (const float*)d_in[12];
    const float* a1_bn_m  = (const float*)d_in[13];
    const float* a1_bn_v  = (const float*)d_in[14];
    const float* a1_proj_w= (const float*)d_in[15];
    const float* a1_proj_b= (const float*)d_in[16];
    const float* t2_bn_g  = (const float*)d_in[17];
    const float* t2_bn_b  = (const float*)d_in[18];
    const float* t2_bn_m  = (const float*)d_in[19];
    const float* t2_bn_v  = (const float*)d_in[20];
    const float* m0_fc1_w = (const float*)d_in[21];
    const float* m0_fc1_b = (const float*)d_in[22];
    const float* m0_fc2_w = (const float*)d_in[23];
    const float* m0_fc2_b = (const float*)d_in[24];
    const float* m1_fc1_w = (const float*)d_in[25];
    const float* m1_fc1_b = (const float*)d_in[26];
    const float* m1_fc2_w = (const float*)d_in[27];
    const float* m1_fc2_b = (const float*)d_in[28];
    const float* m2_fc1_w = (const float*)d_in[29];
    const float* m2_fc1_b = (const float*)d_in[30];
    const float* m2_fc2_w = (const float*)d_in[31];
    const float* m2_fc2_b = (const float*)d_in[32];

    unsigned short* Qb  = (unsigned short*)d_ws;                   // [P][384] bf16
    unsigned short* Ob  = Qb + (size_t)P * 384;                    // [P][192] bf16
    float*          A32 = (float*)(Ob + (size_t)P * 192);          // [P][192] fp32
    unsigned short* Wp  = (unsigned short*)(A32 + (size_t)P * 192);
    const size_t W192 = 384 * 192, W384 = (size_t)384 * 384;
    unsigned short* wb_qkv0 = Wp;
    unsigned short* wb_prj0 = wb_qkv0 + W192;
    unsigned short* wb_qkv1 = wb_prj0 + W192;
    unsigned short* wb_prj1 = wb_qkv1 + W192;
    unsigned short* wb_fc1_0 = wb_prj1 + W192;
    unsigned short* wb_fc1_1 = wb_fc1_0 + W192;
    unsigned short* wb_fc1_2 = wb_fc1_1 + W192;
    unsigned short* wb_fc2_0 = wb_fc1_2 + W192;
    unsigned short* wb_fc2_1 = wb_fc2_0 + W384;
    unsigned short* wb_fc2_2 = wb_fc2_1 + W384;

    dim3 blk(256);
    dim3 blk512(512);
    dim3 gpix(256);
    dim3 gA(512, 2);     // mconvA2: 512 pix-tiles x 2 oc-halves
    dim3 gB(512);
    dim3 ga8(256, 6);
    dim3 ga16(256, 6);

    // ---- one-time prep ----
    wcvt<<<288, blk, 0, stream>>>(a0_qkv_w, wb_qkv0, 360, 180, 192);
    wcvt<<<288, blk, 0, stream>>>(a0_proj_w, wb_prj0, 180, 180, 192);
    wcvt<<<288, blk, 0, stream>>>(a1_qkv_w, wb_qkv1, 360, 180, 192);
    wcvt<<<288, blk, 0, stream>>>(a1_proj_w, wb_prj1, 180, 180, 192);
    wcvt<<<288, blk, 0, stream>>>(m0_fc1_w, wb_fc1_0, 360, 180, 192);
    wcvt<<<288, blk, 0, stream>>>(m1_fc1_w, wb_fc1_1, 360, 180, 192);
    wcvt<<<288, blk, 0, stream>>>(m2_fc1_w, wb_fc1_2, 360, 180, 192);
    wcvt<<<576, blk, 0, stream>>>(m0_fc2_w, wb_fc2_0, 180, 360, 384);
    wcvt<<<576, blk, 0, stream>>>(m1_fc2_w, wb_fc2_1, 180, 360, 384);
    wcvt<<<576, blk, 0, stream>>>(m2_fc2_w, wb_fc2_2, 180, 360, 384);
    padzero<<<gpix, blk, 0, stream>>>(Ob);
    to_nhwc<<<gpix, blk, 0, stream>>>(x, A32);

    // ---- attn stage 0 ----
    mconvA2<0,0,0><<<gA, blk512, 0, stream>>>(A32, wb_qkv0, a0_qkv_b,
        a0_bn_g, a0_bn_b, a0_bn_m, a0_bn_v, Qb);
    mattn<8> <<<ga8,  blk, 0, stream>>>(Qb, Ob, 0);
    mattn<16><<<ga16, blk, 0, stream>>>(Qb, Ob, 0);
    mconvB<180,0,2><<<gB, blk512, 0, stream>>>(Ob, wb_prj0, a0_proj_b, A32, A32);

    // ---- mlp0 ----
    mconvA2<0,1,1><<<gA, blk512, 0, stream>>>(A32, wb_fc1_0, m0_fc1_b,
        nullptr, nullptr, nullptr, nullptr, Qb);
    mconvB<360,1,2><<<gB, blk512, 0, stream>>>(Qb, wb_fc2_0, m0_fc2_b, A32, A32);

    // ---- attn stage 1 ----
    mconvA2<0,0,0><<<gA, blk512, 0, stream>>>(A32, wb_qkv1, a1_qkv_b,
        a1_bn_g, a1_bn_b, a1_bn_m, a1_bn_v, Qb);
    mattn<8> <<<ga8,  blk, 0, stream>>>(Qb, Ob, 4);
    mattn<16><<<ga16, blk, 0, stream>>>(Qb, Ob, 8);
    mconvB<180,0,2><<<gB, blk512, 0, stream>>>(Ob, wb_prj1, a1_proj_b, A32, A32);

    // ---- mlp1 ----
    mconvA2<0,1,1><<<gA, blk512, 0, stream>>>(A32, wb_fc1_1, m1_fc1_b,
        nullptr, nullptr, nullptr, nullptr, Qb);
    mconvB<360,1,2><<<gB, blk512, 0, stream>>>(Qb, wb_fc2_1, m1_fc2_b, A32, A32);

    // ---- pixel mixer: Ob = bf16(x5) ----
    pixmixk<<<dim3(65536 * 45 / 256), blk, 0, stream>>>(A32, t2_bn_g, t2_bn_b,
        t2_bn_m, t2_bn_v, Ob);

    // ---- mlp2 (input Ob bf16 shifted; residual Ob bf16) ----
    mconvA2<1,1,1><<<gA, blk512, 0, stream>>>(Ob, wb_fc1_2, m2_fc1_b,
        nullptr, nullptr, nullptr, nullptr, Qb);
    mconvB<360,1,3><<<gB, blk512, 0, stream>>>(Qb, wb_fc2_2, m2_fc2_b, Ob, A32);

    from_nhwc<<<gpix, blk, 0, stream>>>(A32, (float*)d_out);
}